// Round 1
// baseline (340.972 us; speedup 1.0000x reference)
//
#include <hip/hip_runtime.h>
#include <hip/hip_bf16.h>

#define NN 8192
#define NE 262144

typedef __attribute__((ext_vector_type(8))) short bf16x8;
typedef __attribute__((ext_vector_type(4))) float f32x4;

// ---------------- CSR build ----------------
__global__ __launch_bounds__(256) void k_init(float* __restrict__ deg, int* __restrict__ counts,
                                              int* __restrict__ cnt2) {
  int i = blockIdx.x * 256 + threadIdx.x;
  if (i < NN) { deg[i] = 1.0f; counts[i] = 0; cnt2[i] = 0; }  // deg starts at 1.0 (self-loop w=1)
}

__global__ __launch_bounds__(256) void k_count(const int* __restrict__ ei, const float* __restrict__ w,
                                               float* __restrict__ deg, int* __restrict__ counts) {
  int e = blockIdx.x * 256 + threadIdx.x;
  if (e < NE) {
    int c = ei[NE + e];            // col
    atomicAdd(&deg[c], w[e]);
    atomicAdd(&counts[c], 1);
  }
}

__global__ __launch_bounds__(256) void k_dinv(const float* __restrict__ deg, float* __restrict__ dinv) {
  int i = blockIdx.x * 256 + threadIdx.x;
  if (i < NN) dinv[i] = rsqrtf(deg[i]);   // deg >= 1 > 0 always
}

__global__ __launch_bounds__(1024) void k_scan(const int* __restrict__ counts, int* __restrict__ offs) {
  __shared__ int part[1024];
  int t = threadIdx.x;
  int base = t * 8;
  int local[8];
  int s = 0;
#pragma unroll
  for (int j = 0; j < 8; ++j) { local[j] = counts[base + j]; s += local[j]; }
  part[t] = s;
  __syncthreads();
  for (int off = 1; off < 1024; off <<= 1) {
    int v = (t >= off) ? part[t - off] : 0;
    __syncthreads();
    part[t] += v;
    __syncthreads();
  }
  int run = (t > 0) ? part[t - 1] : 0;
#pragma unroll
  for (int j = 0; j < 8; ++j) { offs[base + j] = run; run += local[j]; }
  if (t == 1023) offs[NN] = run;
}

__global__ __launch_bounds__(256) void k_scatter(const int* __restrict__ ei, const float* __restrict__ w,
                                                 const float* __restrict__ dinv, const int* __restrict__ offs,
                                                 int* __restrict__ cnt2, int* __restrict__ csr_row,
                                                 float* __restrict__ csr_val) {
  int e = blockIdx.x * 256 + threadIdx.x;
  if (e < NE) {
    int r = ei[e], c = ei[NE + e];
    int slot = offs[c] + atomicAdd(&cnt2[c], 1);
    csr_row[slot] = r;
    csr_val[slot] = dinv[r] * w[e] * dinv[c];
  }
}

// ---------------- fp32 tiled GEMM: C[M,Nc] = A[M,K] @ B[K,Nc] ----------------
__global__ __launch_bounds__(256) void k_gemm(const float* __restrict__ A, const float* __restrict__ B,
                                              float* __restrict__ C, int M, int K, int Nc) {
  __shared__ float As[16][68];   // [k][m], stride 68 -> conflict-free b128 reads
  __shared__ float Bs[16][64];   // [k][n]
  int t = threadIdx.x;
  int tx = t & 15, ty = t >> 4;
  int m0 = blockIdx.y * 64, n0 = blockIdx.x * 64;
  int la_r = t >> 2;             // 0..63 row of A tile
  int la_c = (t & 3) * 4;        // k within tile
  int lb_r = t >> 4;             // 0..15 k row of B tile
  int lb_c = (t & 15) * 4;
  const float* Aptr = A + (size_t)(m0 + la_r) * K + la_c;
  const float* Bptr = B + (size_t)lb_r * Nc + n0 + lb_c;
  float acc[4][4] = {};
  for (int k0 = 0; k0 < K; k0 += 16) {
    float4 av = *(const float4*)(Aptr + k0);
    float4 bv = *(const float4*)(Bptr + (size_t)k0 * Nc);
    __syncthreads();
    As[la_c + 0][la_r] = av.x;
    As[la_c + 1][la_r] = av.y;
    As[la_c + 2][la_r] = av.z;
    As[la_c + 3][la_r] = av.w;
    *(float4*)&Bs[lb_r][lb_c] = bv;
    __syncthreads();
#pragma unroll
    for (int kk = 0; kk < 16; ++kk) {
      f32x4 a4 = *(const f32x4*)&As[kk][ty * 4];
      f32x4 b4 = *(const f32x4*)&Bs[kk][tx * 4];
#pragma unroll
      for (int i = 0; i < 4; ++i)
#pragma unroll
        for (int j = 0; j < 4; ++j)
          acc[i][j] = fmaf(a4[i], b4[j], acc[i][j]);
    }
  }
#pragma unroll
  for (int i = 0; i < 4; ++i) {
    f32x4 v = {acc[i][0], acc[i][1], acc[i][2], acc[i][3]};
    *(f32x4*)&C[(size_t)(m0 + ty * 4 + i) * Nc + n0 + tx * 4] = v;
  }
}

// ---------------- CSR aggregation + bias + relu ----------------
__global__ void k_agg(const float* __restrict__ t, const float* __restrict__ dinv,
                      const int* __restrict__ csr_row, const float* __restrict__ csr_val,
                      const int* __restrict__ offs, const float* __restrict__ bias,
                      float* __restrict__ outb, int D) {
  int c = blockIdx.x;
  int d = threadIdx.x;
  float di = dinv[c];
  float acc = di * di * t[(size_t)c * D + d];   // self loop, weight 1
  int s0 = offs[c], s1 = offs[c + 1];
  for (int s = s0; s < s1; ++s) {
    acc += csr_val[s] * t[(size_t)csr_row[s] * D + d];
  }
  outb[(size_t)c * D + d] = fmaxf(acc + bias[d], 0.0f);
}

// ---------------- concat head weights ----------------
__global__ __launch_bounds__(256) void k_cat(const float* __restrict__ Wm, const float* __restrict__ Wsw,
                                             const float* __restrict__ bm, const float* __restrict__ bsv,
                                             float* __restrict__ Wcat, float* __restrict__ bcat) {
  int idx = blockIdx.x * 256 + threadIdx.x;
  if (idx < 256 * 128) {
    int k = idx >> 7, c = idx & 127;
    Wcat[idx] = (c < 64) ? Wm[k * 64 + c] : Wsw[k * 64 + (c - 64)];
  } else if (idx < 256 * 128 + 128) {
    int c = idx - 256 * 128;
    bcat[c] = (c < 64) ? bm[c] : bsv[c - 64];
  }
}

// ---------------- z = noise*exp(log_std)+mean, split bf16 ----------------
__global__ __launch_bounds__(256) void k_z(const float* __restrict__ gms, const float* __restrict__ noise,
                                           __hip_bfloat16* __restrict__ zh, __hip_bfloat16* __restrict__ zl) {
  int idx = blockIdx.x * 256 + threadIdx.x;   // < 8192*64
  int i = idx >> 6, k = idx & 63;
  float mean = gms[(size_t)i * 128 + k];
  float ls = gms[(size_t)i * 128 + 64 + k];
  float z = noise[idx] * __expf(ls) + mean;
  __hip_bfloat16 h = __float2bfloat16(z);
  zh[idx] = h;
  zl[idx] = __float2bfloat16(z - __bfloat162float(h));
}

// ---------------- final: triu(sigmoid(z z^T), 1), split-bf16 MFMA ----------------
__global__ __launch_bounds__(256) void k_final(const short* __restrict__ zh, const short* __restrict__ zl,
                                               float* __restrict__ out) {
  int ti = blockIdx.y, tj = blockIdx.x;
  int ri0 = ti * 128, cj0 = tj * 128;
  if (tj < ti) {                     // entire tile strictly below diagonal -> zeros
    f32x4 zz = {};
    int tr = threadIdx.x >> 5;
    int tc = (threadIdx.x & 31) << 2;
    float* base = out + (size_t)(ri0 + tr) * NN + cj0 + tc;
#pragma unroll
    for (int rr = 0; rr < 128; rr += 8)
      *(f32x4*)(base + (size_t)rr * NN) = zz;
    return;
  }
  int wv = threadIdx.x >> 6;
  int lane = threadIdx.x & 63;
  int wr = wv >> 1, wc = wv & 1;
  int lr = lane & 15;
  int lk = (lane >> 4) << 3;
  int arow = ri0 + wr * 64 + lr;
  int brow = cj0 + wc * 64 + lr;

  bf16x8 ah[4][2], al[4][2];
#pragma unroll
  for (int rb = 0; rb < 4; ++rb)
#pragma unroll
    for (int ks = 0; ks < 2; ++ks) {
      int o = (arow + rb * 16) * 64 + ks * 32 + lk;
      ah[rb][ks] = *(const bf16x8*)(zh + o);
      al[rb][ks] = *(const bf16x8*)(zl + o);
    }
  f32x4 acc[4][4] = {};
#pragma unroll
  for (int cb = 0; cb < 4; ++cb) {
    bf16x8 bh[2], bl[2];
#pragma unroll
    for (int ks = 0; ks < 2; ++ks) {
      int o = (brow + cb * 16) * 64 + ks * 32 + lk;
      bh[ks] = *(const bf16x8*)(zh + o);
      bl[ks] = *(const bf16x8*)(zl + o);
    }
#pragma unroll
    for (int rb = 0; rb < 4; ++rb) {
      f32x4 c = acc[rb][cb];
#pragma unroll
      for (int ks = 0; ks < 2; ++ks) {
        c = __builtin_amdgcn_mfma_f32_16x16x32_bf16(ah[rb][ks], bh[ks], c, 0, 0, 0);
        c = __builtin_amdgcn_mfma_f32_16x16x32_bf16(ah[rb][ks], bl[ks], c, 0, 0, 0);
        c = __builtin_amdgcn_mfma_f32_16x16x32_bf16(al[rb][ks], bh[ks], c, 0, 0, 0);
      }
      acc[rb][cb] = c;
    }
  }
  int orow = ri0 + wr * 64 + ((lane >> 4) << 2);
  int ocol = cj0 + wc * 64 + (lane & 15);
#pragma unroll
  for (int rb = 0; rb < 4; ++rb)
#pragma unroll
    for (int cb = 0; cb < 4; ++cb)
#pragma unroll
      for (int r = 0; r < 4; ++r) {
        int row = orow + rb * 16 + r;
        int col = ocol + cb * 16;
        float v = acc[rb][cb][r];
        float sg = 1.0f / (1.0f + __expf(-v));
        out[(size_t)row * NN + col] = (col > row) ? sg : 0.0f;
      }
}

extern "C" void kernel_launch(void* const* d_in, const int* in_sizes, int n_in,
                              void* d_out, int out_size, void* d_ws, size_t ws_size,
                              hipStream_t stream) {
  (void)in_sizes; (void)n_in; (void)out_size; (void)ws_size;
  const float* x     = (const float*)d_in[0];
  const int*   ei    = (const int*)d_in[1];
  const float* ew    = (const float*)d_in[2];
  const float* noise = (const float*)d_in[3];
  const float* W1    = (const float*)d_in[4];
  const float* b1    = (const float*)d_in[5];
  const float* W2    = (const float*)d_in[6];
  const float* b2    = (const float*)d_in[7];
  const float* Wm    = (const float*)d_in[8];
  const float* bm    = (const float*)d_in[9];
  const float* Wsw   = (const float*)d_in[10];
  const float* bsv   = (const float*)d_in[11];
  float* out = (float*)d_out;

  char* wsb = (char*)d_ws;
  size_t off = 0;
  auto bump = [&](size_t bytes) -> void* {
    void* p = wsb + off;
    off += (bytes + 255) & ~(size_t)255;
    return p;
  };
  float* deg     = (float*)bump((size_t)NN * 4);
  float* dinv    = (float*)bump((size_t)NN * 4);
  int*   counts  = (int*)bump((size_t)NN * 4);
  int*   offs    = (int*)bump((size_t)(NN + 1) * 4);
  int*   cnt2    = (int*)bump((size_t)NN * 4);
  int*   csr_row = (int*)bump((size_t)NE * 4);
  float* csr_val = (float*)bump((size_t)NE * 4);
  float* bufA    = (float*)bump((size_t)NN * 256 * 4);
  float* bufB    = (float*)bump((size_t)NN * 256 * 4);
  float* bufC    = (float*)bump((size_t)NN * 128 * 4);
  float* bufG    = (float*)bump((size_t)NN * 128 * 4);
  float* Wcat    = (float*)bump((size_t)256 * 128 * 4);
  float* bcat    = (float*)bump((size_t)128 * 4);
  __hip_bfloat16* zh = (__hip_bfloat16*)bump((size_t)NN * 64 * 2);
  __hip_bfloat16* zl = (__hip_bfloat16*)bump((size_t)NN * 64 * 2);

  // CSR build
  k_init<<<NN / 256, 256, 0, stream>>>(deg, counts, cnt2);
  k_count<<<NE / 256, 256, 0, stream>>>(ei, ew, deg, counts);
  k_dinv<<<NN / 256, 256, 0, stream>>>(deg, dinv);
  k_scan<<<1, 1024, 0, stream>>>(counts, offs);
  k_scatter<<<NE / 256, 256, 0, stream>>>(ei, ew, dinv, offs, cnt2, csr_row, csr_val);

  // layer 1: h1 = relu(Agg(x@W1) + b1)
  k_gemm<<<dim3(4, 128), 256, 0, stream>>>(x, W1, bufA, NN, 512, 256);
  k_agg<<<NN, 256, 0, stream>>>(bufA, dinv, csr_row, csr_val, offs, b1, bufB, 256);
  // layer 2: h2 = relu(Agg(h1@W2) + b2)
  k_gemm<<<dim3(4, 128), 256, 0, stream>>>(bufB, W2, bufA, NN, 256, 256);
  k_agg<<<NN, 256, 0, stream>>>(bufA, dinv, csr_row, csr_val, offs, b2, bufB, 256);
  // heads: [mean|log_std] = relu(Agg(h2@[Wm|Ws]) + [bm|bs])
  k_cat<<<129, 256, 0, stream>>>(Wm, Wsw, bm, bsv, Wcat, bcat);
  k_gemm<<<dim3(2, 128), 256, 0, stream>>>(bufB, Wcat, bufC, NN, 256, 128);
  k_agg<<<NN, 128, 0, stream>>>(bufC, dinv, csr_row, csr_val, offs, bcat, bufG, 128);
  // z (split bf16)
  k_z<<<NN * 64 / 256, 256, 0, stream>>>(bufG, noise, zh, zl);
  // out = triu(sigmoid(z z^T), 1)
  k_final<<<dim3(64, 64), 256, 0, stream>>>((const short*)zh, (const short*)zl, out);
}

// Round 2
// 274.016 us; speedup vs baseline: 1.2443x; 1.2443x over previous
//
#include <hip/hip_runtime.h>
#include <hip/hip_bf16.h>

#define NN 8192
#define NE 262144

typedef __attribute__((ext_vector_type(8))) short bf16x8;
typedef __attribute__((ext_vector_type(4))) float f32x4;

// ---------------- CSR build ----------------
__global__ __launch_bounds__(256) void k_init(float* __restrict__ deg, int* __restrict__ counts,
                                              int* __restrict__ cnt2) {
  int i = blockIdx.x * 256 + threadIdx.x;
  if (i < NN) { deg[i] = 1.0f; counts[i] = 0; cnt2[i] = 0; }  // deg starts at 1.0 (self-loop w=1)
}

__global__ __launch_bounds__(256) void k_count(const int* __restrict__ ei, const float* __restrict__ w,
                                               float* __restrict__ deg, int* __restrict__ counts) {
  int e = blockIdx.x * 256 + threadIdx.x;
  if (e < NE) {
    int c = ei[NE + e];            // col
    atomicAdd(&deg[c], w[e]);
    atomicAdd(&counts[c], 1);
  }
}

__global__ __launch_bounds__(1024) void k_scan(const int* __restrict__ counts, int* __restrict__ offs) {
  __shared__ int part[1024];
  int t = threadIdx.x;
  int base = t * 8;
  int local[8];
  int s = 0;
#pragma unroll
  for (int j = 0; j < 8; ++j) { local[j] = counts[base + j]; s += local[j]; }
  part[t] = s;
  __syncthreads();
  for (int off = 1; off < 1024; off <<= 1) {
    int v = (t >= off) ? part[t - off] : 0;
    __syncthreads();
    part[t] += v;
    __syncthreads();
  }
  int run = (t > 0) ? part[t - 1] : 0;
#pragma unroll
  for (int j = 0; j < 8; ++j) { offs[base + j] = run; run += local[j]; }
  if (t == 1023) offs[NN] = run;
}

__global__ __launch_bounds__(256) void k_scatter(const int* __restrict__ ei, const float* __restrict__ w,
                                                 const float* __restrict__ deg, const int* __restrict__ offs,
                                                 int* __restrict__ cnt2, int* __restrict__ csr_row,
                                                 float* __restrict__ csr_val) {
  int e = blockIdx.x * 256 + threadIdx.x;
  if (e < NE) {
    int r = ei[e], c = ei[NE + e];
    int slot = offs[c] + atomicAdd(&cnt2[c], 1);
    csr_row[slot] = r;
    csr_val[slot] = rsqrtf(deg[r]) * w[e] * rsqrtf(deg[c]);
  }
}

// ---------------- fp32 tiled GEMM: C[M,Nc] = A[M,K] @ B[K,Nc] ----------------
__global__ __launch_bounds__(256) void k_gemm(const float* __restrict__ A, const float* __restrict__ B,
                                              float* __restrict__ C, int M, int K, int Nc) {
  __shared__ float As[16][68];   // [k][m], stride 68 -> conflict-free b128 reads
  __shared__ float Bs[16][64];   // [k][n]
  int t = threadIdx.x;
  int tx = t & 15, ty = t >> 4;
  int m0 = blockIdx.y * 64, n0 = blockIdx.x * 64;
  int la_r = t >> 2;             // 0..63 row of A tile
  int la_c = (t & 3) * 4;        // k within tile
  int lb_r = t >> 4;             // 0..15 k row of B tile
  int lb_c = (t & 15) * 4;
  const float* Aptr = A + (size_t)(m0 + la_r) * K + la_c;
  const float* Bptr = B + (size_t)lb_r * Nc + n0 + lb_c;
  float acc[4][4] = {};
  for (int k0 = 0; k0 < K; k0 += 16) {
    float4 av = *(const float4*)(Aptr + k0);
    float4 bv = *(const float4*)(Bptr + (size_t)k0 * Nc);
    __syncthreads();
    As[la_c + 0][la_r] = av.x;
    As[la_c + 1][la_r] = av.y;
    As[la_c + 2][la_r] = av.z;
    As[la_c + 3][la_r] = av.w;
    *(float4*)&Bs[lb_r][lb_c] = bv;
    __syncthreads();
#pragma unroll
    for (int kk = 0; kk < 16; ++kk) {
      f32x4 a4 = *(const f32x4*)&As[kk][ty * 4];
      f32x4 b4 = *(const f32x4*)&Bs[kk][tx * 4];
#pragma unroll
      for (int i = 0; i < 4; ++i)
#pragma unroll
        for (int j = 0; j < 4; ++j)
          acc[i][j] = fmaf(a4[i], b4[j], acc[i][j]);
    }
  }
#pragma unroll
  for (int i = 0; i < 4; ++i) {
    f32x4 v = {acc[i][0], acc[i][1], acc[i][2], acc[i][3]};
    *(f32x4*)&C[(size_t)(m0 + ty * 4 + i) * Nc + n0 + tx * 4] = v;
  }
}

// ---------------- CSR aggregation + bias + relu (LDS-staged indices, wave-split edges) ----------------
template <int D>
__global__ __launch_bounds__(256) void k_agg(const float* __restrict__ t, const float* __restrict__ deg,
                                             const int* __restrict__ csr_row, const float* __restrict__ csr_val,
                                             const int* __restrict__ offs, const float* __restrict__ bias,
                                             float* __restrict__ outb) {
  constexpr int V = D / 64;        // floats per lane (4 for D=256, 2 for D=128)
  __shared__ int   srow[256];
  __shared__ float sval[256];
  __shared__ float sacc[4][D];
  int c = blockIdx.x;
  int tid = threadIdx.x;
  int w = tid >> 6, lane = tid & 63;
  int d0 = lane * V;
  float acc[V];
#pragma unroll
  for (int j = 0; j < V; ++j) acc[j] = 0.0f;
  int s0 = offs[c], s1 = offs[c + 1];
  for (int base = s0; base < s1; base += 256) {
    int cnt = s1 - base; if (cnt > 256) cnt = 256;
    __syncthreads();
    if (tid < cnt) { srow[tid] = csr_row[base + tid]; sval[tid] = csr_val[base + tid]; }
    __syncthreads();
    // gathers are now index-independent -> many outstanding loads
    for (int s = w; s < cnt; s += 4) {
      int r = srow[s];
      float v = sval[s];
      const float* p = t + (size_t)r * D + d0;
      if constexpr (V == 4) {
        float4 pv = *(const float4*)p;
        acc[0] = fmaf(v, pv.x, acc[0]);
        acc[1] = fmaf(v, pv.y, acc[1]);
        acc[2] = fmaf(v, pv.z, acc[2]);
        acc[3] = fmaf(v, pv.w, acc[3]);
      } else {
        float2 pv = *(const float2*)p;
        acc[0] = fmaf(v, pv.x, acc[0]);
        acc[1] = fmaf(v, pv.y, acc[1]);
      }
    }
  }
#pragma unroll
  for (int j = 0; j < V; ++j) sacc[w][d0 + j] = acc[j];
  __syncthreads();
  if (tid < 64) {
    float di = rsqrtf(deg[c]);
    float selfw = di * di;
#pragma unroll
    for (int j = 0; j < V; ++j) {
      int d = tid * V + j;
      float a = sacc[0][d] + sacc[1][d] + sacc[2][d] + sacc[3][d];
      a = fmaf(selfw, t[(size_t)c * D + d], a);
      outb[(size_t)c * D + d] = fmaxf(a + bias[d], 0.0f);
    }
  }
}

// ---------------- concat head weights ----------------
__global__ __launch_bounds__(256) void k_cat(const float* __restrict__ Wm, const float* __restrict__ Wsw,
                                             const float* __restrict__ bm, const float* __restrict__ bsv,
                                             float* __restrict__ Wcat, float* __restrict__ bcat) {
  int idx = blockIdx.x * 256 + threadIdx.x;
  if (idx < 256 * 128) {
    int k = idx >> 7, c = idx & 127;
    Wcat[idx] = (c < 64) ? Wm[k * 64 + c] : Wsw[k * 64 + (c - 64)];
  } else if (idx < 256 * 128 + 128) {
    int c = idx - 256 * 128;
    bcat[c] = (c < 64) ? bm[c] : bsv[c - 64];
  }
}

// ---------------- z = noise*exp(log_std)+mean, split bf16 ----------------
__global__ __launch_bounds__(256) void k_z(const float* __restrict__ gms, const float* __restrict__ noise,
                                           __hip_bfloat16* __restrict__ zh, __hip_bfloat16* __restrict__ zl) {
  int idx = blockIdx.x * 256 + threadIdx.x;   // < 8192*64
  int i = idx >> 6, k = idx & 63;
  float mean = gms[(size_t)i * 128 + k];
  float ls = gms[(size_t)i * 128 + 64 + k];
  float z = noise[idx] * __expf(ls) + mean;
  __hip_bfloat16 h = __float2bfloat16(z);
  zh[idx] = h;
  zl[idx] = __float2bfloat16(z - __bfloat162float(h));
}

// ---------------- final: triu(sigmoid(z z^T), 1), split-bf16 MFMA ----------------
__global__ __launch_bounds__(256) void k_final(const short* __restrict__ zh, const short* __restrict__ zl,
                                               float* __restrict__ out) {
  int ti = blockIdx.y, tj = blockIdx.x;
  int ri0 = ti * 128, cj0 = tj * 128;
  if (tj < ti) {                     // entire tile strictly below diagonal -> zeros
    f32x4 zz = {};
    int tr = threadIdx.x >> 5;
    int tc = (threadIdx.x & 31) << 2;
    float* base = out + (size_t)(ri0 + tr) * NN + cj0 + tc;
#pragma unroll
    for (int rr = 0; rr < 128; rr += 8)
      *(f32x4*)(base + (size_t)rr * NN) = zz;
    return;
  }
  int wv = threadIdx.x >> 6;
  int lane = threadIdx.x & 63;
  int wr = wv >> 1, wc = wv & 1;
  int lr = lane & 15;
  int lk = (lane >> 4) << 3;
  int arow = ri0 + wr * 64 + lr;
  int brow = cj0 + wc * 64 + lr;

  bf16x8 ah[4][2], al[4][2];
#pragma unroll
  for (int rb = 0; rb < 4; ++rb)
#pragma unroll
    for (int ks = 0; ks < 2; ++ks) {
      int o = (arow + rb * 16) * 64 + ks * 32 + lk;
      ah[rb][ks] = *(const bf16x8*)(zh + o);
      al[rb][ks] = *(const bf16x8*)(zl + o);
    }
  f32x4 acc[4][4] = {};
#pragma unroll
  for (int cb = 0; cb < 4; ++cb) {
    bf16x8 bh[2], bl[2];
#pragma unroll
    for (int ks = 0; ks < 2; ++ks) {
      int o = (brow + cb * 16) * 64 + ks * 32 + lk;
      bh[ks] = *(const bf16x8*)(zh + o);
      bl[ks] = *(const bf16x8*)(zl + o);
    }
#pragma unroll
    for (int rb = 0; rb < 4; ++rb) {
      f32x4 c = acc[rb][cb];
#pragma unroll
      for (int ks = 0; ks < 2; ++ks) {
        c = __builtin_amdgcn_mfma_f32_16x16x32_bf16(ah[rb][ks], bh[ks], c, 0, 0, 0);
        c = __builtin_amdgcn_mfma_f32_16x16x32_bf16(ah[rb][ks], bl[ks], c, 0, 0, 0);
        c = __builtin_amdgcn_mfma_f32_16x16x32_bf16(al[rb][ks], bh[ks], c, 0, 0, 0);
      }
      acc[rb][cb] = c;
    }
  }
  int orow = ri0 + wr * 64 + ((lane >> 4) << 2);
  int ocol = cj0 + wc * 64 + (lane & 15);
#pragma unroll
  for (int rb = 0; rb < 4; ++rb)
#pragma unroll
    for (int cb = 0; cb < 4; ++cb)
#pragma unroll
      for (int r = 0; r < 4; ++r) {
        int row = orow + rb * 16 + r;
        int col = ocol + cb * 16;
        float v = acc[rb][cb][r];
        float sg = 1.0f / (1.0f + __expf(-v));
        out[(size_t)row * NN + col] = (col > row) ? sg : 0.0f;
      }
}

extern "C" void kernel_launch(void* const* d_in, const int* in_sizes, int n_in,
                              void* d_out, int out_size, void* d_ws, size_t ws_size,
                              hipStream_t stream) {
  (void)in_sizes; (void)n_in; (void)out_size; (void)ws_size;
  const float* x     = (const float*)d_in[0];
  const int*   ei    = (const int*)d_in[1];
  const float* ew    = (const float*)d_in[2];
  const float* noise = (const float*)d_in[3];
  const float* W1    = (const float*)d_in[4];
  const float* b1    = (const float*)d_in[5];
  const float* W2    = (const float*)d_in[6];
  const float* b2    = (const float*)d_in[7];
  const float* Wm    = (const float*)d_in[8];
  const float* bm    = (const float*)d_in[9];
  const float* Wsw   = (const float*)d_in[10];
  const float* bsv   = (const float*)d_in[11];
  float* out = (float*)d_out;

  char* wsb = (char*)d_ws;
  size_t off = 0;
  auto bump = [&](size_t bytes) -> void* {
    void* p = wsb + off;
    off += (bytes + 255) & ~(size_t)255;
    return p;
  };
  float* deg     = (float*)bump((size_t)NN * 4);
  int*   counts  = (int*)bump((size_t)NN * 4);
  int*   offs    = (int*)bump((size_t)(NN + 1) * 4);
  int*   cnt2    = (int*)bump((size_t)NN * 4);
  int*   csr_row = (int*)bump((size_t)NE * 4);
  float* csr_val = (float*)bump((size_t)NE * 4);
  float* bufA    = (float*)bump((size_t)NN * 256 * 4);
  float* bufB    = (float*)bump((size_t)NN * 256 * 4);
  float* bufC    = (float*)bump((size_t)NN * 128 * 4);
  float* bufG    = (float*)bump((size_t)NN * 128 * 4);
  float* Wcat    = (float*)bump((size_t)256 * 128 * 4);
  float* bcat    = (float*)bump((size_t)128 * 4);
  __hip_bfloat16* zh = (__hip_bfloat16*)bump((size_t)NN * 64 * 2);
  __hip_bfloat16* zl = (__hip_bfloat16*)bump((size_t)NN * 64 * 2);

  // CSR build
  k_init<<<NN / 256, 256, 0, stream>>>(deg, counts, cnt2);
  k_count<<<NE / 256, 256, 0, stream>>>(ei, ew, deg, counts);
  k_scan<<<1, 1024, 0, stream>>>(counts, offs);
  k_scatter<<<NE / 256, 256, 0, stream>>>(ei, ew, deg, offs, cnt2, csr_row, csr_val);

  // layer 1: h1 = relu(Agg(x@W1) + b1)
  k_gemm<<<dim3(4, 128), 256, 0, stream>>>(x, W1, bufA, NN, 512, 256);
  k_agg<256><<<NN, 256, 0, stream>>>(bufA, deg, csr_row, csr_val, offs, b1, bufB);
  // layer 2: h2 = relu(Agg(h1@W2) + b2)
  k_gemm<<<dim3(4, 128), 256, 0, stream>>>(bufB, W2, bufA, NN, 256, 256);
  k_agg<256><<<NN, 256, 0, stream>>>(bufA, deg, csr_row, csr_val, offs, b2, bufB);
  // heads: [mean|log_std] = relu(Agg(h2@[Wm|Ws]) + [bm|bs])
  k_cat<<<129, 256, 0, stream>>>(Wm, Wsw, bm, bsv, Wcat, bcat);
  k_gemm<<<dim3(2, 128), 256, 0, stream>>>(bufB, Wcat, bufC, NN, 256, 128);
  k_agg<128><<<NN, 256, 0, stream>>>(bufC, deg, csr_row, csr_val, offs, bcat, bufG);
  // z (split bf16)
  k_z<<<NN * 64 / 256, 256, 0, stream>>>(bufG, noise, zh, zl);
  // out = triu(sigmoid(z z^T), 1)
  k_final<<<dim3(64, 64), 256, 0, stream>>>((const short*)zh, (const short*)zl, out);
}